// Round 15
// baseline (55.610 us; speedup 1.0000x reference)
//
#include <hip/hip_runtime.h>
#include <math.h>

#define BATCH 8
#define CIN 64
#define COUT 64
#define HH 128
#define WW 128
#define HW (HH*WW)
#define TPX 64       // pixels per block (half row)
#define KDIM 576
#define NR 5         // staged rows  (h-2 .. h+2, clamped)
#define NC 69        // staged cols  (w0-2 .. w0+66, clamped)
#define NSLOT (NR*NC)          // 345 col-slots
#define NITEM (NSLOT*8)        // 2760 16B-chunks

typedef __attribute__((ext_vector_type(8))) short short8;
typedef __attribute__((ext_vector_type(4))) float f32x4;
typedef __attribute__((ext_vector_type(4))) unsigned int u32x4;
typedef _Float16 h2   __attribute__((ext_vector_type(2)));
typedef _Float16 h8   __attribute__((ext_vector_type(8)));

__device__ __forceinline__ short f2h(float f) {
    union { _Float16 h; short s; } u;
    u.h = (_Float16)f;
    return u.s;
}

// ---------------- Kernel 1: transpose + weight reorder (merged) ----------------
__global__ void __launch_bounds__(256) prep_kernel(const float* __restrict__ x,
                                                   unsigned short* __restrict__ xT,
                                                   const float* __restrict__ w_dcn,
                                                   const float* __restrict__ w_off,
                                                   unsigned short* __restrict__ wt2,
                                                   unsigned short* __restrict__ wtoff2) {
    if (blockIdx.x < 4096) {
        int idx = blockIdx.x * 256 + threadIdx.x;   // 1,048,576 total
        int c8 = idx & 7;
        int w  = (idx >> 3) & 127;
        int h  = (idx >> 10) & 127;
        int b  = idx >> 17;
        const float* xp = x + (((size_t)(b * 64 + c8 * 8) * 128 + h) * 128 + w);
        short8 o;
#pragma unroll
        for (int j = 0; j < 8; ++j)
            o[j] = f2h(xp[(size_t)j * HW]);
        *(short8*)(xT + (size_t)idx * 8) = o;
        return;
    }
    int gid = (blockIdx.x - 4096) * 256 + threadIdx.x;
    if (gid < 72 * 64) {
        int frag = gid >> 6, lane = gid & 63;
        int kf = frag >> 3, s = (frag >> 2) & 1, m = frag & 3;
        int o = m * 16 + (lane & 15);
        int cb = s * 32 + (lane >> 4) * 8;
        short8 v;
#pragma unroll
        for (int j = 0; j < 8; ++j)
            v[j] = f2h(w_dcn[(o * 64 + cb + j) * 9 + kf]);
        *(short8*)(wt2 + (size_t)gid * 8) = v;
    } else {
        int g2 = gid - 72 * 64;
        if (g2 < 36 * 64) {
            int frag = g2 >> 6, lane = g2 & 63;
            int kk = frag >> 1, m = frag & 1;
            int kf = kk >> 1;
            int o = m * 16 + (lane & 15);
            int cb = (kk & 1) * 32 + (lane >> 4) * 8;
            short8 v;
#pragma unroll
            for (int j = 0; j < 8; ++j)
                v[j] = (o < 27) ? f2h(w_off[(o * 64 + cb + j) * 9 + kf]) : (short)0;
            *(short8*)(wtoff2 + (size_t)g2 * 8) = v;
        }
    }
}

// packed-entry corner load: 1 ds_read_b128 + int ops + 8 corner ds_reads
#define LOAD_CORNERS(KF)                                                    \
    do {                                                                    \
        u32x4 e = *(const u32x4*)(s_geo8 + (size_t)(pxl * 9 + (KF)) * 16);  \
        int msk = (int)e.w >> 31;          /* all-ones if out-of-window */  \
        oow |= (e.w >> 31) << (KF);                                         \
        unsigned u0 = e.x & ~msk, u1 = e.y & ~msk;                          \
        union { unsigned u; h2 h; } c0_, c1_;                               \
        c0_.u = u0; c1_.u = u1;                                             \
        W0 = (h2){c0_.h.x, c0_.h.x}; W1 = (h2){c0_.h.y, c0_.h.y};           \
        W2 = (h2){c1_.h.x, c1_.h.x}; W3 = (h2){c1_.h.y, c1_.h.y};           \
        int base = (int)(e.z & ~msk);                                       \
        int sw00 = (int)(e.w & 0x70u);                                      \
        int sw01 = (int)((e.w >> 8) & 0x70u);                               \
        int sw10 = (int)((e.w >> 16) & 0x70u);                              \
        int sw11 = (int)((e.w >> 24) & 0x70u);                              \
        int q40 = g4 << 4;                                                  \
        int q41 = 64 + q40;                                                 \
        V0 = *(const h8*)(s_x + base + (q40 ^ sw00));                       \
        V1 = *(const h8*)(s_x + base + 128 + (q40 ^ sw01));                 \
        V2 = *(const h8*)(s_x + base + 8832 + (q40 ^ sw10));                \
        V3 = *(const h8*)(s_x + base + 8960 + (q40 ^ sw11));                \
        V4 = *(const h8*)(s_x + base + (q41 ^ sw00));                       \
        V5 = *(const h8*)(s_x + base + 128 + (q41 ^ sw01));                 \
        V6 = *(const h8*)(s_x + base + 8832 + (q41 ^ sw10));                \
        V7 = *(const h8*)(s_x + base + 8960 + (q41 ^ sw11));                \
    } while (0)

// ---------------- Kernel 2: fused; geometry hoisted to packed LDS entries ----------------
__global__ void __launch_bounds__(256, 3) fused_dcn_kernel(
        const unsigned short* __restrict__ xT,
        const unsigned short* __restrict__ wtoff2,
        const float* __restrict__ b_off,
        const unsigned short* __restrict__ wt2,
        float* __restrict__ out) {
    __shared__ char  s_x[NSLOT * 128];          // 44,160 B  [slot][chunk ^ (c&7) ^ r5]
    __shared__ float s_geo[TPX * 36];           // 9,216 B: raw {dy,dx,m,-} -> packed entry
    char* s_geo8 = (char*)s_geo;

    int t = threadIdx.x;
    int blk0 = blockIdx.x;
    int blk = (blk0 & 7) * 256 + (blk0 >> 3);   // XCD swizzle (2048 = 8*256, bijective)
    int b = blk >> 8;
    int rem = blk & 255;
    int h = rem >> 1;                            // tile = 64 px of one row
    int w0 = (rem & 1) << 6;

    int lane = t & 63;
    int wv = t >> 6;
    int l15 = lane & 15;
    int g4 = lane >> 4;
    int pxl = wv * 16 + l15;                    // local pixel 0..63
    int wg = w0 + pxl;                          // global col

    const unsigned short* xTb = xT + (size_t)b * HW * 64;

    // ---- phase 0: stage x window into LDS (issue-early / write-late) ----
    {
        short8 v[11];
        int cs[11], cl[11];
#pragma unroll
        for (int it = 0; it < 11; ++it) {
            int i = it * 256 + t;
            if (i < NITEM) {
                int c_slot = i >> 3;
                cl[it] = i & 7;
                int r5 = c_slot / NC;
                int c  = c_slot - r5 * NC;
                cs[it] = c_slot;
                int row_src = min(max(h - 2 + r5, 0), 127);
                int col_src = min(max(w0 - 2 + c, 0), 127);
                v[it] = *(const short8*)(xTb + ((size_t)row_src * 128 + col_src) * 64 + cl[it] * 8);
            }
        }
#pragma unroll
        for (int it = 0; it < 11; ++it) {
            int i = it * 256 + t;
            if (i < NITEM) {
                int c_slot = cs[it];
                int r5 = c_slot / NC;
                int c = c_slot - r5 * NC;
                int baddr = c_slot * 128 + ((cl[it] ^ (c & 7) ^ r5) << 4);
                *(short8*)(s_x + baddr) = v[it];
            }
        }
    }
    __syncthreads();

    // ---- phase A: offset conv (27ch) via f16 MFMA; scatter raw {dy,dx,sig(m)} ----
    {
        f32x4 ca0 = {0.f, 0.f, 0.f, 0.f};
        f32x4 ca1 = {0.f, 0.f, 0.f, 0.f};
#pragma unroll
        for (int kk = 0; kk < 18; ++kk) {
            int kf = kk >> 1;
            int ky = kf / 3, kx = kf % 3;
            int cq = (kk & 1) * 4 + g4;
            int row = h - 1 + ky;
            int col = wg - 1 + kx;
            int cc = pxl + 1 + kx;              // window col index
            int wr = ky + 1;                    // window row 1..3
            int addr = (wr * NC + cc) * 128 + ((cq ^ (cc & 7) ^ wr) << 4);
            h8 bfrag = *(const h8*)(s_x + addr);
            if (!((unsigned)row < 128u && (unsigned)col < 128u))
                bfrag = (h8){0, 0, 0, 0, 0, 0, 0, 0};
            h8 a0 = *(const h8*)(wtoff2 + (size_t)(kk * 2 + 0) * 512 + lane * 8);
            h8 a1 = *(const h8*)(wtoff2 + (size_t)(kk * 2 + 1) * 512 + lane * 8);
            ca0 = __builtin_amdgcn_mfma_f32_16x16x32_f16(a0, bfrag, ca0, 0, 0, 0);
            ca1 = __builtin_amdgcn_mfma_f32_16x16x32_f16(a1, bfrag, ca1, 0, 0, 0);
        }
        float* gp = s_geo + pxl * 36;
        int ch0 = g4 * 4;
#pragma unroll
        for (int r = 0; r < 4; ++r) {
            int ch = ch0 + r;                   // 0..15 -> dy/dx of kf 0..7
            float v1 = ca0[r] + b_off[ch];
            gp[(ch >> 1) * 4 + (ch & 1)] = v1;
            int ch2 = 16 + ch;                  // 16..31
            if (ch2 < 18) {
                float v2 = ca1[r] + b_off[ch2];
                gp[8 * 4 + (ch2 - 16)] = v2;
            } else if (ch2 < 27) {
                float v2 = ca1[r] + b_off[ch2];
                gp[(ch2 - 18) * 4 + 2] = 1.0f / (1.0f + __expf(-v2));
            }
        }
    }
    __syncthreads();

    // ---- phase B: transform raw geo -> packed entry, in place (288 items) ----
    for (int idx = t; idx < TPX * 9; idx += 256) {
        int px = idx / 9, kf = idx - (idx / 9) * 9;
        float* gp = s_geo + (size_t)idx * 4;
        float dy = gp[0], dxo = gp[1], m = gp[2];
        float py  = (float)(h - 1 + kf / 3) + dy;
        float pxf = (float)(w0 + px - 1 + kf % 3) + dxo;
        float y0f = floorf(py), x0f = floorf(pxf);
        float wy1 = py - y0f, wx1 = pxf - x0f;
        float wy0 = 1.f - wy1, wx0 = 1.f - wx1;
        int y0 = (int)y0f, x0 = (int)x0f;
        float ay0 = ((unsigned)y0 < 128u) ? wy0 * m : 0.f;
        float ay1 = ((unsigned)(y0 + 1) < 128u) ? wy1 * m : 0.f;
        float ax0 = ((unsigned)x0 < 128u) ? wx0 : 0.f;
        float ax1 = ((unsigned)(x0 + 1) < 128u) ? wx1 : 0.f;
        float w00 = ay0 * ax0, w01 = ay0 * ax1;
        float w10 = ay1 * ax0, w11 = ay1 * ax1;
        union { struct { _Float16 a, b; } s; unsigned u; } cv;
        cv.s.a = (_Float16)w00; cv.s.b = (_Float16)w01;
        unsigned uw0 = cv.u;
        cv.s.a = (_Float16)w10; cv.s.b = (_Float16)w11;
        unsigned uw1 = cv.u;
        int r50 = y0 - (h - 2);
        int c0  = x0 - (w0 - 2);
        bool inw = (r50 >= 0) & (r50 <= 3) & (c0 >= 0) & (c0 <= 67);
        unsigned wd2, wd3;
        if (inw) {
            wd2 = (unsigned)((r50 * NC + c0) * 128);
            unsigned s00 = (unsigned)(((c0 & 7) ^ (r50 & 7)) << 4);
            unsigned s01 = (unsigned)((((c0 + 1) & 7) ^ (r50 & 7)) << 4);
            unsigned s10 = (unsigned)(((c0 & 7) ^ ((r50 + 1) & 7)) << 4);
            unsigned s11 = (unsigned)((((c0 + 1) & 7) ^ ((r50 + 1) & 7)) << 4);
            wd3 = s00 | (s01 << 8) | (s10 << 16) | (s11 << 24);
        } else {
            int y0c = min(max(y0, -1), 127) + 1;   // 0..128
            int x0c = min(max(x0, -1), 127) + 1;
            wd2 = ((unsigned)y0c << 16) | (unsigned)x0c;
            wd3 = 0x80000000u;
        }
        unsigned* wp = (unsigned*)gp;
        wp[0] = uw0; wp[1] = uw1; wp[2] = wd2; wp[3] = wd3;
    }
    __syncthreads();

    // ---- main loop: packed-entry reads, 1-deep pipelined ----
    f32x4 acc0 = {0.f, 0.f, 0.f, 0.f};
    f32x4 acc1 = {0.f, 0.f, 0.f, 0.f};
    f32x4 acc2 = {0.f, 0.f, 0.f, 0.f};
    f32x4 acc3 = {0.f, 0.f, 0.f, 0.f};

    h8 a_cur[8], a_nxt[8];
#pragma unroll
    for (int q = 0; q < 8; ++q)
        a_cur[q] = *(const h8*)(wt2 + (size_t)q * 512 + lane * 8);

    h8 V0, V1, V2, V3, V4, V5, V6, V7;
    h2 W0, W1, W2, W3;
    unsigned oow = 0;
    LOAD_CORNERS(0);

#pragma unroll
    for (int kf = 0; kf < 9; ++kf) {
        // interp (consumes V/W)
        h8 bf0, bf1;
        {
            const h2* p0 = (const h2*)&V0;
            const h2* p1 = (const h2*)&V1;
            const h2* p2 = (const h2*)&V2;
            const h2* p3 = (const h2*)&V3;
            h2* bp = (h2*)&bf0;
#pragma unroll
            for (int j = 0; j < 4; ++j) {
                h2 r = p3[j] * W3;
                r = p2[j] * W2 + r;
                r = p1[j] * W1 + r;
                r = p0[j] * W0 + r;
                bp[j] = r;
            }
            const h2* q0 = (const h2*)&V4;
            const h2* q1 = (const h2*)&V5;
            const h2* q2 = (const h2*)&V6;
            const h2* q3 = (const h2*)&V7;
            h2* bq = (h2*)&bf1;
#pragma unroll
            for (int j = 0; j < 4; ++j) {
                h2 r = q3[j] * W3;
                r = q2[j] * W2 + r;
                r = q1[j] * W1 + r;
                r = q0[j] * W0 + r;
                bq[j] = r;
            }
        }

        // issue next-kf corner reads + A-frag prefetch; overlaps MFMA cluster
        if (kf < 8) {
            LOAD_CORNERS(kf + 1);
#pragma unroll
            for (int q = 0; q < 8; ++q)
                a_nxt[q] = *(const h8*)(wt2 + (size_t)((kf + 1) * 8 + q) * 512 + lane * 8);
        }

        __builtin_amdgcn_s_setprio(1);
        acc0 = __builtin_amdgcn_mfma_f32_16x16x32_f16(a_cur[0], bf0, acc0, 0, 0, 0);
        acc1 = __builtin_amdgcn_mfma_f32_16x16x32_f16(a_cur[1], bf0, acc1, 0, 0, 0);
        acc2 = __builtin_amdgcn_mfma_f32_16x16x32_f16(a_cur[2], bf0, acc2, 0, 0, 0);
        acc3 = __builtin_amdgcn_mfma_f32_16x16x32_f16(a_cur[3], bf0, acc3, 0, 0, 0);
        acc0 = __builtin_amdgcn_mfma_f32_16x16x32_f16(a_cur[4], bf1, acc0, 0, 0, 0);
        acc1 = __builtin_amdgcn_mfma_f32_16x16x32_f16(a_cur[5], bf1, acc1, 0, 0, 0);
        acc2 = __builtin_amdgcn_mfma_f32_16x16x32_f16(a_cur[6], bf1, acc2, 0, 0, 0);
        acc3 = __builtin_amdgcn_mfma_f32_16x16x32_f16(a_cur[7], bf1, acc3, 0, 0, 0);
        __builtin_amdgcn_s_setprio(0);

#pragma unroll
        for (int q = 0; q < 8; ++q)
            a_cur[q] = a_nxt[q];
    }

    // ---- rare fixup: samples outside the staged window (contribution was 0) ----
    if (__builtin_expect(__any((int)(oow != 0)), 0)) {
#pragma unroll 1
        for (int kf = 0; kf < 9; ++kf) {
            if (!__any((int)((oow >> kf) & 1u))) continue;
            u32x4 e = *(const u32x4*)(s_geo8 + (size_t)(pxl * 9 + kf) * 16);
            int keep = -(int)(e.w >> 31);          // all-ones if mine
            unsigned u0 = e.x & (unsigned)keep, u1 = e.y & (unsigned)keep;
            union { unsigned u; h2 h; } c0_, c1_;
            c0_.u = u0; c1_.u = u1;
            h2 X0 = {c0_.h.x, c0_.h.x}, X1 = {c0_.h.y, c0_.h.y};
            h2 X2 = {c1_.h.x, c1_.h.x}, X3 = {c1_.h.y, c1_.h.y};
            int y0c = (int)((e.z >> 16) & 0xffu) - 1;
            int x0c = (int)(e.z & 0xffu) - 1;
            int y0a = max(y0c, 0) * 8192;
            int y1a = min(y0c + 1, 127) * 8192;
            int x0a = max(x0c, 0) * 64;
            int x1a = min(x0c + 1, 127) * 64;
            h8 af[8];
#pragma unroll
            for (int q = 0; q < 8; ++q)
                af[q] = *(const h8*)(wt2 + (size_t)(kf * 8 + q) * 512 + lane * 8);
#pragma unroll
            for (int s = 0; s < 2; ++s) {
                int cb = s * 32 + g4 * 8;
                h8 v00 = *(const h8*)(xTb + y0a + x0a + cb);
                h8 v01 = *(const h8*)(xTb + y0a + x1a + cb);
                h8 v10 = *(const h8*)(xTb + y1a + x0a + cb);
                h8 v11 = *(const h8*)(xTb + y1a + x1a + cb);
                h8 bf;
                const h2* p0 = (const h2*)&v00;
                const h2* p1 = (const h2*)&v01;
                const h2* p2 = (const h2*)&v10;
                const h2* p3 = (const h2*)&v11;
                h2* bp = (h2*)&bf;
#pragma unroll
                for (int j = 0; j < 4; ++j) {
                    h2 r = p3[j] * X3;
                    r = p2[j] * X2 + r;
                    r = p1[j] * X1 + r;
                    r = p0[j] * X0 + r;
                    bp[j] = r;
                }
                acc0 = __builtin_amdgcn_mfma_f32_16x16x32_f16(af[s * 4 + 0], bf, acc0, 0, 0, 0);
                acc1 = __builtin_amdgcn_mfma_f32_16x16x32_f16(af[s * 4 + 1], bf, acc1, 0, 0, 0);
                acc2 = __builtin_amdgcn_mfma_f32_16x16x32_f16(af[s * 4 + 2], bf, acc2, 0, 0, 0);
                acc3 = __builtin_amdgcn_mfma_f32_16x16x32_f16(af[s * 4 + 3], bf, acc3, 0, 0, 0);
            }
        }
    }

    // ---- store ----
    float* obp = out + (size_t)b * COUT * HW + (size_t)h * WW + wg;
    int or0 = g4 * 4;
#pragma unroll
    for (int r = 0; r < 4; ++r) {
        obp[(size_t)(or0 + r) * HW]      = acc0[r];
        obp[(size_t)(16 + or0 + r) * HW] = acc1[r];
        obp[(size_t)(32 + or0 + r) * HW] = acc2[r];
        obp[(size_t)(48 + or0 + r) * HW] = acc3[r];
    }
}

extern "C" void kernel_launch(void* const* d_in, const int* in_sizes, int n_in,
                              void* d_out, int out_size, void* d_ws, size_t ws_size,
                              hipStream_t stream) {
    (void)in_sizes; (void)n_in; (void)out_size; (void)ws_size;
    const float* x        = (const float*)d_in[0];
    const float* w_offset = (const float*)d_in[1];
    const float* b_offset = (const float*)d_in[2];
    const float* w_dcn    = (const float*)d_in[3];
    float* out = (float*)d_out;

    unsigned short* xT     = (unsigned short*)d_ws;                      // 16,777,216 B
    unsigned short* wt2    = (unsigned short*)((char*)d_ws + 16777216);  // 73,728 B
    unsigned short* wtoff2 = (unsigned short*)((char*)d_ws + 16850944);  // 36,864 B

    prep_kernel<<<4096 + 27, 256, 0, stream>>>(x, xT, w_dcn, w_offset, wt2, wtoff2);
    fused_dcn_kernel<<<2048, 256, 0, stream>>>(xT, wtoff2, b_offset, wt2, out);
}

// Round 16
// 53.127 us; speedup vs baseline: 1.0468x; 1.0468x over previous
//
#include <hip/hip_runtime.h>
#include <math.h>

#define BATCH 8
#define CIN 64
#define COUT 64
#define HH 128
#define WW 128
#define HW (HH*WW)
#define TPX 64       // pixels per block (half row)
#define KDIM 576
#define NR 5         // staged rows  (h-2 .. h+2, clamped)
#define NC 69        // staged cols  (w0-2 .. w0+66, clamped)
#define NSLOT (NR*NC)          // 345 col-slots
#define NITEM (NSLOT*8)        // 2760 16B-chunks

typedef __attribute__((ext_vector_type(8))) short short8;
typedef __attribute__((ext_vector_type(4))) float f32x4;
typedef __attribute__((ext_vector_type(4))) unsigned int u32x4;
typedef _Float16 h2   __attribute__((ext_vector_type(2)));
typedef _Float16 h8   __attribute__((ext_vector_type(8)));

__device__ __forceinline__ short f2h(float f) {
    union { _Float16 h; short s; } u;
    u.h = (_Float16)f;
    return u.s;
}

// ---------------- Kernel 1: LDS-tiled transpose + weight reorder ----------------
// blocks 0..2047 : x[b][c][h][w0..w0+63] fp32 -> xT[b][h][w][c] fp16 (via LDS tile)
// blocks 2048+   : weights -> MFMA-fragment order fp16
__global__ void __launch_bounds__(256) prep_kernel(const float* __restrict__ x,
                                                   unsigned short* __restrict__ xT,
                                                   const float* __restrict__ w_dcn,
                                                   const float* __restrict__ w_off,
                                                   unsigned short* __restrict__ wt2,
                                                   unsigned short* __restrict__ wtoff2) {
    __shared__ unsigned short s_t[4096];        // 8 KB: [w64][c64] chunk-swizzled
    int blk = blockIdx.x;
    int t = threadIdx.x;
    if (blk < 2048) {
        int b = blk >> 8;
        int hw = blk & 255;
        int h = hw >> 1;
        int w0 = (hw & 1) << 6;
        int c = t & 63;
        int seg = t >> 6;                       // 16-w segment
        int c8 = c >> 3;
        const float* xp = x + (((size_t)(b * 64 + c) * 128 + h) * 128 + w0 + seg * 16);
        f32x4 A0 = *(const f32x4*)(xp);
        f32x4 A1 = *(const f32x4*)(xp + 4);
        f32x4 A2 = *(const f32x4*)(xp + 8);
        f32x4 A3 = *(const f32x4*)(xp + 12);
        float vals[16] = {A0[0],A0[1],A0[2],A0[3], A1[0],A1[1],A1[2],A1[3],
                          A2[0],A2[1],A2[2],A2[3], A3[0],A3[1],A3[2],A3[3]};
#pragma unroll
        for (int j = 0; j < 16; ++j) {
            int wl = seg * 16 + j;
            s_t[wl * 64 + ((c8 ^ (wl & 7)) * 8) + (c & 7)] = (unsigned short)f2h(vals[j]);
        }
        __syncthreads();
        unsigned short* xo = xT + (size_t)b * HW * 64 + ((size_t)h * 128 + w0) * 64;
#pragma unroll
        for (int uu = 0; uu < 2; ++uu) {
            int u = uu * 256 + t;
            int w = u >> 3;
            int cc8 = u & 7;
            short8 v = *(const short8*)(s_t + w * 64 + ((cc8 ^ (w & 7)) * 8));
            *(short8*)(xo + (size_t)w * 64 + cc8 * 8) = v;
        }
        return;
    }
    int gid = (blk - 2048) * 256 + t;
    if (gid < 72 * 64) {
        int frag = gid >> 6, lane = gid & 63;
        int kf = frag >> 3, s = (frag >> 2) & 1, m = frag & 3;
        int o = m * 16 + (lane & 15);
        int cb = s * 32 + (lane >> 4) * 8;
        short8 v;
#pragma unroll
        for (int j = 0; j < 8; ++j)
            v[j] = f2h(w_dcn[(o * 64 + cb + j) * 9 + kf]);
        *(short8*)(wt2 + (size_t)gid * 8) = v;
    } else {
        int g2 = gid - 72 * 64;
        if (g2 < 36 * 64) {
            int frag = g2 >> 6, lane = g2 & 63;
            int kk = frag >> 1, m = frag & 1;
            int kf = kk >> 1;
            int o = m * 16 + (lane & 15);
            int cb = (kk & 1) * 32 + (lane >> 4) * 8;
            short8 v;
#pragma unroll
            for (int j = 0; j < 8; ++j)
                v[j] = (o < 27) ? f2h(w_off[(o * 64 + cb + j) * 9 + kf]) : (short)0;
            *(short8*)(wtoff2 + (size_t)g2 * 8) = v;
        }
    }
}

#define READ_ENTRY(KF, E)                                                   \
    E = *(const u32x4*)(s_geo8 + (size_t)(pxl * 9 + (KF)) * 16)

// decode entry E -> W0..W3, oow bit, issue 8 corner ds_reads into V0..V7
#define CORNERS_FROM(E, KF)                                                 \
    do {                                                                    \
        int msk = (int)E.w >> 31;          /* all-ones if out-of-window */  \
        oow |= (E.w >> 31) << (KF);                                         \
        unsigned u0 = E.x & ~msk, u1 = E.y & ~msk;                          \
        union { unsigned u; h2 h; } c0_, c1_;                               \
        c0_.u = u0; c1_.u = u1;                                             \
        W0 = (h2){c0_.h.x, c0_.h.x}; W1 = (h2){c0_.h.y, c0_.h.y};           \
        W2 = (h2){c1_.h.x, c1_.h.x}; W3 = (h2){c1_.h.y, c1_.h.y};           \
        int base = (int)(E.z & ~msk);                                       \
        int sw00 = (int)(E.w & 0x70u);                                      \
        int sw01 = (int)((E.w >> 8) & 0x70u);                               \
        int sw10 = (int)((E.w >> 16) & 0x70u);                              \
        int sw11 = (int)((E.w >> 24) & 0x70u);                              \
        int q40 = g4 << 4;                                                  \
        int q41 = 64 + q40;                                                 \
        V0 = *(const h8*)(s_x + base + (q40 ^ sw00));                       \
        V1 = *(const h8*)(s_x + base + 128 + (q40 ^ sw01));                 \
        V2 = *(const h8*)(s_x + base + 8832 + (q40 ^ sw10));                \
        V3 = *(const h8*)(s_x + base + 8960 + (q40 ^ sw11));                \
        V4 = *(const h8*)(s_x + base + (q41 ^ sw00));                       \
        V5 = *(const h8*)(s_x + base + 128 + (q41 ^ sw01));                 \
        V6 = *(const h8*)(s_x + base + 8832 + (q41 ^ sw10));                \
        V7 = *(const h8*)(s_x + base + 8960 + (q41 ^ sw11));                \
    } while (0)

// ---------------- Kernel 2: fused; 2-deep entry pipeline ----------------
__global__ void __launch_bounds__(256, 3) fused_dcn_kernel(
        const unsigned short* __restrict__ xT,
        const unsigned short* __restrict__ wtoff2,
        const float* __restrict__ b_off,
        const unsigned short* __restrict__ wt2,
        float* __restrict__ out) {
    __shared__ char  s_x[NSLOT * 128];          // 44,160 B  [slot][chunk ^ (c&7) ^ r5]
    __shared__ float s_geo[TPX * 36];           // 9,216 B: raw {dy,dx,m,-} -> packed entry
    char* s_geo8 = (char*)s_geo;

    int t = threadIdx.x;
    int blk0 = blockIdx.x;
    int blk = (blk0 & 7) * 256 + (blk0 >> 3);   // XCD swizzle (2048 = 8*256, bijective)
    int b = blk >> 8;
    int rem = blk & 255;
    int h = rem >> 1;                            // tile = 64 px of one row
    int w0 = (rem & 1) << 6;

    int lane = t & 63;
    int wv = t >> 6;
    int l15 = lane & 15;
    int g4 = lane >> 4;
    int pxl = wv * 16 + l15;                    // local pixel 0..63
    int wg = w0 + pxl;                          // global col

    const unsigned short* xTb = xT + (size_t)b * HW * 64;

    // ---- phase 0: stage x window into LDS (issue-early / write-late) ----
    {
        short8 v[11];
        int cs[11], cl[11];
#pragma unroll
        for (int it = 0; it < 11; ++it) {
            int i = it * 256 + t;
            if (i < NITEM) {
                int c_slot = i >> 3;
                cl[it] = i & 7;
                int r5 = c_slot / NC;
                int c  = c_slot - r5 * NC;
                cs[it] = c_slot;
                int row_src = min(max(h - 2 + r5, 0), 127);
                int col_src = min(max(w0 - 2 + c, 0), 127);
                v[it] = *(const short8*)(xTb + ((size_t)row_src * 128 + col_src) * 64 + cl[it] * 8);
            }
        }
#pragma unroll
        for (int it = 0; it < 11; ++it) {
            int i = it * 256 + t;
            if (i < NITEM) {
                int c_slot = cs[it];
                int r5 = c_slot / NC;
                int c = c_slot - r5 * NC;
                int baddr = c_slot * 128 + ((cl[it] ^ (c & 7) ^ r5) << 4);
                *(short8*)(s_x + baddr) = v[it];
            }
        }
    }
    __syncthreads();

    // ---- phase A: offset conv (27ch) via f16 MFMA; scatter raw {dy,dx,sig(m)} ----
    {
        f32x4 ca0 = {0.f, 0.f, 0.f, 0.f};
        f32x4 ca1 = {0.f, 0.f, 0.f, 0.f};
#pragma unroll
        for (int kk = 0; kk < 18; ++kk) {
            int kf = kk >> 1;
            int ky = kf / 3, kx = kf % 3;
            int cq = (kk & 1) * 4 + g4;
            int row = h - 1 + ky;
            int col = wg - 1 + kx;
            int cc = pxl + 1 + kx;              // window col index
            int wr = ky + 1;                    // window row 1..3
            int addr = (wr * NC + cc) * 128 + ((cq ^ (cc & 7) ^ wr) << 4);
            h8 bfrag = *(const h8*)(s_x + addr);
            if (!((unsigned)row < 128u && (unsigned)col < 128u))
                bfrag = (h8){0, 0, 0, 0, 0, 0, 0, 0};
            h8 a0 = *(const h8*)(wtoff2 + (size_t)(kk * 2 + 0) * 512 + lane * 8);
            h8 a1 = *(const h8*)(wtoff2 + (size_t)(kk * 2 + 1) * 512 + lane * 8);
            ca0 = __builtin_amdgcn_mfma_f32_16x16x32_f16(a0, bfrag, ca0, 0, 0, 0);
            ca1 = __builtin_amdgcn_mfma_f32_16x16x32_f16(a1, bfrag, ca1, 0, 0, 0);
        }
        float* gp = s_geo + pxl * 36;
        int ch0 = g4 * 4;
#pragma unroll
        for (int r = 0; r < 4; ++r) {
            int ch = ch0 + r;                   // 0..15 -> dy/dx of kf 0..7
            float v1 = ca0[r] + b_off[ch];
            gp[(ch >> 1) * 4 + (ch & 1)] = v1;
            int ch2 = 16 + ch;                  // 16..31
            if (ch2 < 18) {
                float v2 = ca1[r] + b_off[ch2];
                gp[8 * 4 + (ch2 - 16)] = v2;
            } else if (ch2 < 27) {
                float v2 = ca1[r] + b_off[ch2];
                gp[(ch2 - 18) * 4 + 2] = 1.0f / (1.0f + __expf(-v2));
            }
        }
    }
    __syncthreads();

    // ---- phase B: transform raw geo -> packed entry, in place (288 items) ----
    for (int idx = t; idx < TPX * 9; idx += 256) {
        int px = idx / 9, kf = idx - (idx / 9) * 9;
        float* gp = s_geo + (size_t)idx * 4;
        float dy = gp[0], dxo = gp[1], m = gp[2];
        float py  = (float)(h - 1 + kf / 3) + dy;
        float pxf = (float)(w0 + px - 1 + kf % 3) + dxo;
        float y0f = floorf(py), x0f = floorf(pxf);
        float wy1 = py - y0f, wx1 = pxf - x0f;
        float wy0 = 1.f - wy1, wx0 = 1.f - wx1;
        int y0 = (int)y0f, x0 = (int)x0f;
        float ay0 = ((unsigned)y0 < 128u) ? wy0 * m : 0.f;
        float ay1 = ((unsigned)(y0 + 1) < 128u) ? wy1 * m : 0.f;
        float ax0 = ((unsigned)x0 < 128u) ? wx0 : 0.f;
        float ax1 = ((unsigned)(x0 + 1) < 128u) ? wx1 : 0.f;
        float w00 = ay0 * ax0, w01 = ay0 * ax1;
        float w10 = ay1 * ax0, w11 = ay1 * ax1;
        union { struct { _Float16 a, b; } s; unsigned u; } cv;
        cv.s.a = (_Float16)w00; cv.s.b = (_Float16)w01;
        unsigned uw0 = cv.u;
        cv.s.a = (_Float16)w10; cv.s.b = (_Float16)w11;
        unsigned uw1 = cv.u;
        int r50 = y0 - (h - 2);
        int c0  = x0 - (w0 - 2);
        bool inw = (r50 >= 0) & (r50 <= 3) & (c0 >= 0) & (c0 <= 67);
        unsigned wd2, wd3;
        if (inw) {
            wd2 = (unsigned)((r50 * NC + c0) * 128);
            unsigned s00 = (unsigned)(((c0 & 7) ^ (r50 & 7)) << 4);
            unsigned s01 = (unsigned)((((c0 + 1) & 7) ^ (r50 & 7)) << 4);
            unsigned s10 = (unsigned)(((c0 & 7) ^ ((r50 + 1) & 7)) << 4);
            unsigned s11 = (unsigned)((((c0 + 1) & 7) ^ ((r50 + 1) & 7)) << 4);
            wd3 = s00 | (s01 << 8) | (s10 << 16) | (s11 << 24);
        } else {
            int y0c = min(max(y0, -1), 127) + 1;   // 0..128
            int x0c = min(max(x0, -1), 127) + 1;
            wd2 = ((unsigned)y0c << 16) | (unsigned)x0c;
            wd3 = 0x80000000u;
        }
        unsigned* wp = (unsigned*)gp;
        wp[0] = uw0; wp[1] = uw1; wp[2] = wd2; wp[3] = wd3;
    }
    __syncthreads();

    // ---- main loop: 2-deep entry pipeline, 1-deep corner pipeline ----
    f32x4 acc0 = {0.f, 0.f, 0.f, 0.f};
    f32x4 acc1 = {0.f, 0.f, 0.f, 0.f};
    f32x4 acc2 = {0.f, 0.f, 0.f, 0.f};
    f32x4 acc3 = {0.f, 0.f, 0.f, 0.f};

    h8 a_cur[8], a_nxt[8];
#pragma unroll
    for (int q = 0; q < 8; ++q)
        a_cur[q] = *(const h8*)(wt2 + (size_t)q * 512 + lane * 8);

    h8 V0, V1, V2, V3, V4, V5, V6, V7;
    h2 W0, W1, W2, W3;
    unsigned oow = 0;
    u32x4 e_cur, e_nxt;
    READ_ENTRY(0, e_cur);
    CORNERS_FROM(e_cur, 0);
    READ_ENTRY(1, e_nxt);

#pragma unroll
    for (int kf = 0; kf < 9; ++kf) {
        // interp (consumes V/W)
        h8 bf0, bf1;
        {
            const h2* p0 = (const h2*)&V0;
            const h2* p1 = (const h2*)&V1;
            const h2* p2 = (const h2*)&V2;
            const h2* p3 = (const h2*)&V3;
            h2* bp = (h2*)&bf0;
#pragma unroll
            for (int j = 0; j < 4; ++j) {
                h2 r = p3[j] * W3;
                r = p2[j] * W2 + r;
                r = p1[j] * W1 + r;
                r = p0[j] * W0 + r;
                bp[j] = r;
            }
            const h2* q0 = (const h2*)&V4;
            const h2* q1 = (const h2*)&V5;
            const h2* q2 = (const h2*)&V6;
            const h2* q3 = (const h2*)&V7;
            h2* bq = (h2*)&bf1;
#pragma unroll
            for (int j = 0; j < 4; ++j) {
                h2 r = q3[j] * W3;
                r = q2[j] * W2 + r;
                r = q1[j] * W1 + r;
                r = q0[j] * W0 + r;
                bq[j] = r;
            }
        }

        // issue next-kf corner reads (from e_nxt, already resident),
        // prefetch entry kf+2 and next A-frags; all overlap the MFMA cluster
        if (kf < 8) {
            CORNERS_FROM(e_nxt, kf + 1);
            if (kf < 7) { READ_ENTRY(kf + 2, e_nxt); }
#pragma unroll
            for (int q = 0; q < 8; ++q)
                a_nxt[q] = *(const h8*)(wt2 + (size_t)((kf + 1) * 8 + q) * 512 + lane * 8);
        }

        __builtin_amdgcn_s_setprio(1);
        acc0 = __builtin_amdgcn_mfma_f32_16x16x32_f16(a_cur[0], bf0, acc0, 0, 0, 0);
        acc1 = __builtin_amdgcn_mfma_f32_16x16x32_f16(a_cur[1], bf0, acc1, 0, 0, 0);
        acc2 = __builtin_amdgcn_mfma_f32_16x16x32_f16(a_cur[2], bf0, acc2, 0, 0, 0);
        acc3 = __builtin_amdgcn_mfma_f32_16x16x32_f16(a_cur[3], bf0, acc3, 0, 0, 0);
        acc0 = __builtin_amdgcn_mfma_f32_16x16x32_f16(a_cur[4], bf1, acc0, 0, 0, 0);
        acc1 = __builtin_amdgcn_mfma_f32_16x16x32_f16(a_cur[5], bf1, acc1, 0, 0, 0);
        acc2 = __builtin_amdgcn_mfma_f32_16x16x32_f16(a_cur[6], bf1, acc2, 0, 0, 0);
        acc3 = __builtin_amdgcn_mfma_f32_16x16x32_f16(a_cur[7], bf1, acc3, 0, 0, 0);
        __builtin_amdgcn_s_setprio(0);

#pragma unroll
        for (int q = 0; q < 8; ++q)
            a_cur[q] = a_nxt[q];
    }

    // ---- rare fixup: samples outside the staged window (contribution was 0) ----
    if (__builtin_expect(__any((int)(oow != 0)), 0)) {
#pragma unroll 1
        for (int kf = 0; kf < 9; ++kf) {
            if (!__any((int)((oow >> kf) & 1u))) continue;
            u32x4 e = *(const u32x4*)(s_geo8 + (size_t)(pxl * 9 + kf) * 16);
            int keep = -(int)(e.w >> 31);          // all-ones if mine
            unsigned u0 = e.x & (unsigned)keep, u1 = e.y & (unsigned)keep;
            union { unsigned u; h2 h; } c0_, c1_;
            c0_.u = u0; c1_.u = u1;
            h2 X0 = {c0_.h.x, c0_.h.x}, X1 = {c0_.h.y, c0_.h.y};
            h2 X2 = {c1_.h.x, c1_.h.x}, X3 = {c1_.h.y, c1_.h.y};
            int y0c = (int)((e.z >> 16) & 0xffu) - 1;
            int x0c = (int)(e.z & 0xffu) - 1;
            int y0a = max(y0c, 0) * 8192;
            int y1a = min(y0c + 1, 127) * 8192;
            int x0a = max(x0c, 0) * 64;
            int x1a = min(x0c + 1, 127) * 64;
            h8 af[8];
#pragma unroll
            for (int q = 0; q < 8; ++q)
                af[q] = *(const h8*)(wt2 + (size_t)(kf * 8 + q) * 512 + lane * 8);
#pragma unroll
            for (int s = 0; s < 2; ++s) {
                int cb = s * 32 + g4 * 8;
                h8 v00 = *(const h8*)(xTb + y0a + x0a + cb);
                h8 v01 = *(const h8*)(xTb + y0a + x1a + cb);
                h8 v10 = *(const h8*)(xTb + y1a + x0a + cb);
                h8 v11 = *(const h8*)(xTb + y1a + x1a + cb);
                h8 bf;
                const h2* p0 = (const h2*)&v00;
                const h2* p1 = (const h2*)&v01;
                const h2* p2 = (const h2*)&v10;
                const h2* p3 = (const h2*)&v11;
                h2* bp = (h2*)&bf;
#pragma unroll
                for (int j = 0; j < 4; ++j) {
                    h2 r = p3[j] * X3;
                    r = p2[j] * X2 + r;
                    r = p1[j] * X1 + r;
                    r = p0[j] * X0 + r;
                    bp[j] = r;
                }
                acc0 = __builtin_amdgcn_mfma_f32_16x16x32_f16(af[s * 4 + 0], bf, acc0, 0, 0, 0);
                acc1 = __builtin_amdgcn_mfma_f32_16x16x32_f16(af[s * 4 + 1], bf, acc1, 0, 0, 0);
                acc2 = __builtin_amdgcn_mfma_f32_16x16x32_f16(af[s * 4 + 2], bf, acc2, 0, 0, 0);
                acc3 = __builtin_amdgcn_mfma_f32_16x16x32_f16(af[s * 4 + 3], bf, acc3, 0, 0, 0);
            }
        }
    }

    // ---- store ----
    float* obp = out + (size_t)b * COUT * HW + (size_t)h * WW + wg;
    int or0 = g4 * 4;
#pragma unroll
    for (int r = 0; r < 4; ++r) {
        obp[(size_t)(or0 + r) * HW]      = acc0[r];
        obp[(size_t)(16 + or0 + r) * HW] = acc1[r];
        obp[(size_t)(32 + or0 + r) * HW] = acc2[r];
        obp[(size_t)(48 + or0 + r) * HW] = acc3[r];
    }
}

extern "C" void kernel_launch(void* const* d_in, const int* in_sizes, int n_in,
                              void* d_out, int out_size, void* d_ws, size_t ws_size,
                              hipStream_t stream) {
    (void)in_sizes; (void)n_in; (void)out_size; (void)ws_size;
    const float* x        = (const float*)d_in[0];
    const float* w_offset = (const float*)d_in[1];
    const float* b_offset = (const float*)d_in[2];
    const float* w_dcn    = (const float*)d_in[3];
    float* out = (float*)d_out;

    unsigned short* xT     = (unsigned short*)d_ws;                      // 16,777,216 B
    unsigned short* wt2    = (unsigned short*)((char*)d_ws + 16777216);  // 73,728 B
    unsigned short* wtoff2 = (unsigned short*)((char*)d_ws + 16850944);  // 36,864 B

    prep_kernel<<<2048 + 27, 256, 0, stream>>>(x, xT, w_dcn, w_offset, wt2, wtoff2);
    fused_dcn_kernel<<<2048, 256, 0, stream>>>(xT, wtoff2, b_offset, wt2, out);
}